// Round 1
// baseline (789.250 us; speedup 1.0000x reference)
//
#include <hip/hip_runtime.h>
#include <hip/hip_bf16.h>
#include <cstdint>

typedef __bf16 bf16;
typedef __bf16 bf16x8 __attribute__((ext_vector_type(8)));
typedef float f32x4 __attribute__((ext_vector_type(4)));

#define DEV __device__ __forceinline__

DEV f32x4 mfma16(bf16x8 a, bf16x8 b, f32x4 c) {
  return __builtin_amdgcn_mfma_f32_16x16x32_bf16(a, b, c, 0, 0, 0);
}

// async global->LDS, 16B per lane; LDS dest = wave-uniform base + lane*16
DEV void gl2lds16(const void* g, void* l) {
  __builtin_amdgcn_global_load_lds((__attribute__((address_space(1))) void*)g,
                                   (__attribute__((address_space(3))) void*)l,
                                   16, 0, 0);
}

// ---------------- fp32 -> bf16 convert (8 elems/thread) ----------------
__global__ void cvt_f32_bf16(const float* __restrict__ s, bf16* __restrict__ d, int n) {
  int i = (blockIdx.x * 256 + threadIdx.x) * 8;
  if (i >= n) return;
  f32x4 a = *(const f32x4*)(s + i);
  f32x4 b = *(const f32x4*)(s + i + 4);
  bf16x8 o;
#pragma unroll
  for (int e = 0; e < 4; ++e) { o[e] = (bf16)a[e]; o[e + 4] = (bf16)b[e]; }
  *(bf16x8*)(d + i) = o;
}

// ---------------- GEMM C = A(MxK) * B(NxK)^T, all K-contiguous ----------------
// 128x128 tile, BK=32, 4 waves of 64x64, 16x16x32 bf16 MFMA, global_load_lds staging.
template <typename OutT>
__global__ __launch_bounds__(256) void gemm_bt(const bf16* __restrict__ A,
                                               const bf16* __restrict__ B,
                                               OutT* __restrict__ C,
                                               int M, int N, int K) {
  __shared__ bf16 As[128 * 32];
  __shared__ bf16 Bs[128 * 32];
  const int tid = threadIdx.x;
  const int lane = tid & 63, w = tid >> 6;
  const int wm = w & 1, wn = w >> 1;
  const int quad = lane >> 4, r = lane & 15;
  const long mBase = (long)blockIdx.y * 128, nBase = (long)blockIdx.x * 128;
  f32x4 acc[4][4];
#pragma unroll
  for (int i = 0; i < 4; ++i)
#pragma unroll
    for (int j = 0; j < 4; ++j) acc[i][j] = f32x4{0.f, 0.f, 0.f, 0.f};

  for (int k0 = 0; k0 < K; k0 += 32) {
    __syncthreads();  // prior iter's LDS reads done
#pragma unroll
    for (int j = 0; j < 2; ++j) {
      const int c = w * 128 + j * 64 + lane;  // 16B chunk id, row-major [128][32]
      const int row = c >> 2, kc = c & 3;
      gl2lds16(A + (mBase + row) * (long)K + k0 + kc * 8,
               (char*)As + (w * 128 + j * 64) * 16);
      gl2lds16(B + (nBase + row) * (long)K + k0 + kc * 8,
               (char*)Bs + (w * 128 + j * 64) * 16);
    }
    __syncthreads();  // staging visible (vmcnt(0) drained by barrier)
    bf16x8 af[4], bfr[4];
#pragma unroll
    for (int i = 0; i < 4; ++i) {
      af[i]  = *(const bf16x8*)(&As[(wm * 64 + i * 16 + r) * 32 + quad * 8]);
      bfr[i] = *(const bf16x8*)(&Bs[(wn * 64 + i * 16 + r) * 32 + quad * 8]);
    }
#pragma unroll
    for (int mi = 0; mi < 4; ++mi)
#pragma unroll
      for (int ni = 0; ni < 4; ++ni)
        acc[mi][ni] = mfma16(af[mi], bfr[ni], acc[mi][ni]);
  }
  // C/D layout: row = quad*4+reg, col = lane&15 (verified m89/m91)
#pragma unroll
  for (int mi = 0; mi < 4; ++mi)
#pragma unroll
    for (int ni = 0; ni < 4; ++ni)
#pragma unroll
      for (int rg = 0; rg < 4; ++rg) {
        long row = mBase + wm * 64 + mi * 16 + quad * 4 + rg;
        long col = nBase + wn * 64 + ni * 16 + r;
        C[row * N + col] = (OutT)acc[mi][ni][rg];
      }
}

// ---------------- RoPE (neox) in place on q (32 heads) + k (8 heads) ----------------
__global__ void rope_kernel(bf16* __restrict__ qkv, const int* __restrict__ pos) {
  int idx = blockIdx.x * 256 + threadIdx.x;  // T*40*64 threads
  int d = idx & 63;
  int rest = idx >> 6;
  int head = rest % 40;
  int t = rest / 40;
  bf16* p = qkv + (long)t * 6144 + head * 128;
  float x1 = (float)p[d], x2 = (float)p[d + 64];
  // inv_freq = 10000^(-d/64)
  float inv_freq = __builtin_expf(-(float)d * (9.210340371976184f / 64.0f));
  float fr = (float)pos[t] * inv_freq;
  float c = __builtin_cosf(fr), s = __builtin_sinf(fr);
  p[d]      = (bf16)(x1 * c - x2 * s);
  p[d + 64] = (bf16)(x2 * c + x1 * s);
}

// ---------------- flash attention, causal, GQA 4:1 ----------------
// grid = (T/128 q-tiles, H heads); 4 waves, each 32 q-rows; kv tiles of 64.
__global__ __launch_bounds__(256) void attn_kernel(const bf16* __restrict__ qkv,
                                                   bf16* __restrict__ out) {
  constexpr int LDK = 136, LDV = 72, LDP = 72;  // padded strides (bank-conflict free pairs)
  constexpr float SCL2 = 0.08838834764831845f * 1.4426950408889634f;  // 1/sqrt(128)*log2(e)
  __shared__ bf16 Ks[64 * LDK];    // K tile  [kv=64][d=128]
  __shared__ bf16 Vt[128 * LDV];   // V tile transposed [d=128][kv=64]
  __shared__ bf16 Ps[128 * LDP];   // P       [q=128][kv=64]
  const int tid = threadIdx.x;
  const int lane = tid & 63, w = tid >> 6;
  const int quad = lane >> 4, r = lane & 15;
  const int qt = blockIdx.x, h = blockIdx.y;
  const int kvh = h >> 2;
  const int qbase = qt * 128;
  const int rowq = qbase + w * 32;

  // Q fragments direct from global (A-operand: m=lane&15, k=quad*8..+8)
  bf16x8 qf[2][4];
#pragma unroll
  for (int mi = 0; mi < 2; ++mi)
#pragma unroll
    for (int ks = 0; ks < 4; ++ks)
      qf[mi][ks] = *(const bf16x8*)(qkv + (long)(rowq + mi * 16 + r) * 6144 +
                                    h * 128 + ks * 32 + quad * 8);

  f32x4 of[2][8];
#pragma unroll
  for (int mi = 0; mi < 2; ++mi)
#pragma unroll
    for (int di = 0; di < 8; ++di) of[mi][di] = f32x4{0.f, 0.f, 0.f, 0.f};
  float mrun[2][4], lrun[2][4];
#pragma unroll
  for (int mi = 0; mi < 2; ++mi)
#pragma unroll
    for (int rg = 0; rg < 4; ++rg) { mrun[mi][rg] = -__builtin_inff(); lrun[mi][rg] = 0.f; }

  const int ntiles = qt * 2 + 2;
  for (int kt = 0; kt < ntiles; ++kt) {
    const int kvbase = kt * 64;
    __syncthreads();  // prior iter's Ks/Vt reads done
    // stage K tile: 1024 16B chunks over 256 threads
#pragma unroll
    for (int ii = 0; ii < 4; ++ii) {
      const int c = tid + 256 * ii;
      const int row = c >> 4, dc = c & 15;
      *(bf16x8*)(&Ks[row * LDK + dc * 8]) =
          *(const bf16x8*)(qkv + (long)(kvbase + row) * 6144 + 4096 + kvh * 128 + dc * 8);
    }
    // stage V transposed
#pragma unroll
    for (int ii = 0; ii < 4; ++ii) {
      const int c = tid + 256 * ii;
      const int j = c >> 4, dc = c & 15;
      bf16x8 v = *(const bf16x8*)(qkv + (long)(kvbase + j) * 6144 + 5120 + kvh * 128 + dc * 8);
#pragma unroll
      for (int e = 0; e < 8; ++e) Vt[(dc * 8 + e) * LDV + j] = v[e];
    }
    __syncthreads();

    // S = Q K^T  (wave: 32 q x 64 kv)
    f32x4 sacc[2][4];
#pragma unroll
    for (int mi = 0; mi < 2; ++mi)
#pragma unroll
      for (int ni = 0; ni < 4; ++ni) sacc[mi][ni] = f32x4{0.f, 0.f, 0.f, 0.f};
#pragma unroll
    for (int ks = 0; ks < 4; ++ks) {
      bf16x8 kf[4];
#pragma unroll
      for (int ni = 0; ni < 4; ++ni)
        kf[ni] = *(const bf16x8*)(&Ks[(ni * 16 + r) * LDK + ks * 32 + quad * 8]);
#pragma unroll
      for (int mi = 0; mi < 2; ++mi)
#pragma unroll
        for (int ni = 0; ni < 4; ++ni)
          sacc[mi][ni] = mfma16(qf[mi][ks], kf[ni], sacc[mi][ni]);
    }

    // causal mask + online softmax. S layout: row=quad*4+rg (+mi*16), col=lane&15 (+ni*16)
    float mtile[2][4];
#pragma unroll
    for (int mi = 0; mi < 2; ++mi)
#pragma unroll
      for (int rg = 0; rg < 4; ++rg) mtile[mi][rg] = -1e30f;
#pragma unroll
    for (int mi = 0; mi < 2; ++mi) {
      const int rq = rowq + mi * 16 + quad * 4;
#pragma unroll
      for (int ni = 0; ni < 4; ++ni) {
        const int ck = kvbase + ni * 16 + r;
#pragma unroll
        for (int rg = 0; rg < 4; ++rg) {
          float sv = sacc[mi][ni][rg];
          sv = (ck > rq + rg) ? -1e30f : sv;
          sacc[mi][ni][rg] = sv;
          mtile[mi][rg] = fmaxf(mtile[mi][rg], sv);
        }
      }
    }
#pragma unroll
    for (int mi = 0; mi < 2; ++mi)
#pragma unroll
      for (int rg = 0; rg < 4; ++rg) {
        float v = mtile[mi][rg];
        v = fmaxf(v, __shfl_xor(v, 1));
        v = fmaxf(v, __shfl_xor(v, 2));
        v = fmaxf(v, __shfl_xor(v, 4));
        v = fmaxf(v, __shfl_xor(v, 8));
        mtile[mi][rg] = v;
      }
    float alpha[2][4], rsum[2][4];
#pragma unroll
    for (int mi = 0; mi < 2; ++mi)
#pragma unroll
      for (int rg = 0; rg < 4; ++rg) {
        float mnew = fmaxf(mrun[mi][rg], mtile[mi][rg]);
        alpha[mi][rg] = __builtin_exp2f((mrun[mi][rg] - mnew) * SCL2);
        mrun[mi][rg] = mnew;
        rsum[mi][rg] = 0.f;
      }
#pragma unroll
    for (int mi = 0; mi < 2; ++mi)
#pragma unroll
      for (int ni = 0; ni < 4; ++ni)
#pragma unroll
        for (int rg = 0; rg < 4; ++rg) {
          float p = __builtin_exp2f((sacc[mi][ni][rg] - mrun[mi][rg]) * SCL2);
          rsum[mi][rg] += p;
          Ps[(w * 32 + mi * 16 + quad * 4 + rg) * LDP + ni * 16 + r] = (bf16)p;
        }
#pragma unroll
    for (int mi = 0; mi < 2; ++mi)
#pragma unroll
      for (int rg = 0; rg < 4; ++rg) {
        float v = rsum[mi][rg];
        v += __shfl_xor(v, 1);
        v += __shfl_xor(v, 2);
        v += __shfl_xor(v, 4);
        v += __shfl_xor(v, 8);
        lrun[mi][rg] = lrun[mi][rg] * alpha[mi][rg] + v;
      }
#pragma unroll
    for (int mi = 0; mi < 2; ++mi)
#pragma unroll
      for (int di = 0; di < 8; ++di)
#pragma unroll
        for (int rg = 0; rg < 4; ++rg) of[mi][di][rg] *= alpha[mi][rg];

    __syncthreads();  // Ps write->read ordering

    // O += P * V  (A = P rows of this wave; B = Vt[n=d][k=j])
#pragma unroll
    for (int js = 0; js < 2; ++js) {
      bf16x8 pf[2];
#pragma unroll
      for (int mi = 0; mi < 2; ++mi)
        pf[mi] = *(const bf16x8*)(&Ps[(w * 32 + mi * 16 + r) * LDP + js * 32 + quad * 8]);
#pragma unroll
      for (int di = 0; di < 8; ++di) {
        bf16x8 vf = *(const bf16x8*)(&Vt[(di * 16 + r) * LDV + js * 32 + quad * 8]);
#pragma unroll
        for (int mi = 0; mi < 2; ++mi)
          of[mi][di] = mfma16(pf[mi], vf, of[mi][di]);
      }
    }
  }

  // epilogue: O /= l, write bf16 (T x 4096)
#pragma unroll
  for (int mi = 0; mi < 2; ++mi)
#pragma unroll
    for (int rg = 0; rg < 4; ++rg) {
      const float inv = 1.f / lrun[mi][rg];
      const long t = rowq + mi * 16 + quad * 4 + rg;
#pragma unroll
      for (int di = 0; di < 8; ++di)
        out[t * 4096 + h * 128 + di * 16 + r] = (bf16)(of[mi][di][rg] * inv);
    }
}

// ---------------- host ----------------
extern "C" void kernel_launch(void* const* d_in, const int* in_sizes, int n_in,
                              void* d_out, int out_size, void* d_ws, size_t ws_size,
                              hipStream_t stream) {
  const int* positions = (const int*)d_in[0];
  const float* hidden = (const float*)d_in[1];
  const float* w_qkv = (const float*)d_in[2];
  const float* w_o = (const float*)d_in[3];
  float* out = (float*)d_out;

  char* ws = (char*)d_ws;
  bf16* hid_b  = (bf16*)(ws);                  // 2048x4096            16.78 MB
  bf16* wqkv_b = (bf16*)(ws + 16777216);       // 6144x4096            50.33 MB
  bf16* wo_b   = (bf16*)(ws + 67108864);       // 4096x4096            33.55 MB
  bf16* qkv    = (bf16*)(ws + 100663296);      // 2048x6144            25.17 MB
  bf16* attn   = (bf16*)(ws + 125829120);      // 2048x4096            16.78 MB

  cvt_f32_bf16<<<8388608 / 2048, 256, 0, stream>>>(hidden, hid_b, 8388608);
  cvt_f32_bf16<<<25165824 / 2048, 256, 0, stream>>>(w_qkv, wqkv_b, 25165824);
  cvt_f32_bf16<<<16777216 / 2048, 256, 0, stream>>>(w_o, wo_b, 16777216);
  gemm_bt<bf16><<<dim3(48, 16), 256, 0, stream>>>(hid_b, wqkv_b, qkv, 2048, 6144, 4096);
  rope_kernel<<<5242880 / 256, 256, 0, stream>>>(qkv, positions);
  attn_kernel<<<dim3(16, 32), 256, 0, stream>>>(qkv, attn);
  gemm_bt<float><<<dim3(32, 16), 256, 0, stream>>>(attn, wo_b, out, 2048, 4096, 4096);
}

// Round 2
// 584.888 us; speedup vs baseline: 1.3494x; 1.3494x over previous
//
#include <hip/hip_runtime.h>
#include <hip/hip_bf16.h>
#include <cstdint>

typedef __bf16 bf16;
typedef __bf16 bf16x8 __attribute__((ext_vector_type(8)));
typedef float f32x4 __attribute__((ext_vector_type(4)));

#define DEV __device__ __forceinline__

DEV f32x4 mfma16(bf16x8 a, bf16x8 b, f32x4 c) {
  return __builtin_amdgcn_mfma_f32_16x16x32_bf16(a, b, c, 0, 0, 0);
}

// async global->LDS, 16B per lane; LDS dest = wave-uniform base + lane*16
DEV void gl2lds16(const void* g, void* l) {
  __builtin_amdgcn_global_load_lds((__attribute__((address_space(1))) void*)g,
                                   (__attribute__((address_space(3))) void*)l,
                                   16, 0, 0);
}

// ---------------- fp32 -> bf16 convert (8 elems/thread) ----------------
__global__ void cvt_f32_bf16(const float* __restrict__ s, bf16* __restrict__ d, int n) {
  int i = (blockIdx.x * 256 + threadIdx.x) * 8;
  if (i >= n) return;
  f32x4 a = *(const f32x4*)(s + i);
  f32x4 b = *(const f32x4*)(s + i + 4);
  bf16x8 o;
#pragma unroll
  for (int e = 0; e < 4; ++e) { o[e] = (bf16)a[e]; o[e + 4] = (bf16)b[e]; }
  *(bf16x8*)(d + i) = o;
}

// ---------------- GEMM C = A(MxK) * B(NxK)^T, all K-contiguous ----------------
template <typename OutT>
__global__ __launch_bounds__(256) void gemm_bt(const bf16* __restrict__ A,
                                               const bf16* __restrict__ B,
                                               OutT* __restrict__ C,
                                               int M, int N, int K) {
  __shared__ bf16 As[128 * 32];
  __shared__ bf16 Bs[128 * 32];
  const int tid = threadIdx.x;
  const int lane = tid & 63, w = tid >> 6;
  const int wm = w & 1, wn = w >> 1;
  const int quad = lane >> 4, r = lane & 15;
  const long mBase = (long)blockIdx.y * 128, nBase = (long)blockIdx.x * 128;
  f32x4 acc[4][4];
#pragma unroll
  for (int i = 0; i < 4; ++i)
#pragma unroll
    for (int j = 0; j < 4; ++j) acc[i][j] = f32x4{0.f, 0.f, 0.f, 0.f};

  for (int k0 = 0; k0 < K; k0 += 32) {
    __syncthreads();
#pragma unroll
    for (int j = 0; j < 2; ++j) {
      const int c = w * 128 + j * 64 + lane;
      const int row = c >> 2, kc = c & 3;
      gl2lds16(A + (mBase + row) * (long)K + k0 + kc * 8,
               (char*)As + (w * 128 + j * 64) * 16);
      gl2lds16(B + (nBase + row) * (long)K + k0 + kc * 8,
               (char*)Bs + (w * 128 + j * 64) * 16);
    }
    __syncthreads();
    bf16x8 af[4], bfr[4];
#pragma unroll
    for (int i = 0; i < 4; ++i) {
      af[i]  = *(const bf16x8*)(&As[(wm * 64 + i * 16 + r) * 32 + quad * 8]);
      bfr[i] = *(const bf16x8*)(&Bs[(wn * 64 + i * 16 + r) * 32 + quad * 8]);
    }
#pragma unroll
    for (int mi = 0; mi < 4; ++mi)
#pragma unroll
      for (int ni = 0; ni < 4; ++ni)
        acc[mi][ni] = mfma16(af[mi], bfr[ni], acc[mi][ni]);
  }
#pragma unroll
  for (int mi = 0; mi < 4; ++mi)
#pragma unroll
    for (int ni = 0; ni < 4; ++ni)
#pragma unroll
      for (int rg = 0; rg < 4; ++rg) {
        long row = mBase + wm * 64 + mi * 16 + quad * 4 + rg;
        long col = nBase + wn * 64 + ni * 16 + r;
        C[row * N + col] = (OutT)acc[mi][ni][rg];
      }
}

// ---------------- RoPE (neox) in place on q (32 heads) + k (8 heads) ----------------
__global__ void rope_kernel(bf16* __restrict__ qkv, const int* __restrict__ pos) {
  int idx = blockIdx.x * 256 + threadIdx.x;
  int d = idx & 63;
  int rest = idx >> 6;
  int head = rest % 40;
  int t = rest / 40;
  bf16* p = qkv + (long)t * 6144 + head * 128;
  float x1 = (float)p[d], x2 = (float)p[d + 64];
  float inv_freq = __builtin_expf(-(float)d * (9.210340371976184f / 64.0f));
  float fr = (float)pos[t] * inv_freq;
  float c = __builtin_cosf(fr), s = __builtin_sinf(fr);
  p[d]      = (bf16)(x1 * c - x2 * s);
  p[d + 64] = (bf16)(x2 * c + x1 * s);
}

// ---------------- flash attention v2: causal, GQA 4:1, pair-balanced ----------------
// grid = (16 pairs, 32 heads). Block = 256 thr / 4 waves, each wave 16 q-rows.
// Block processes q-tile p then q-tile 31-p => every block does exactly 33 kv-tiles.
__global__ __launch_bounds__(256, 3) void attn_kernel(const bf16* __restrict__ qkv,
                                                      bf16* __restrict__ out) {
  constexpr int LDV = 72, LDP = 72;
  constexpr float SCL2 = 0.08838834764831845f * 1.4426950408889634f;  // 1/sqrt(128)*log2(e)
  __shared__ bf16 Ks[64 * 128];   // K tile [kv=64][d=128], chunk-XOR-swizzled
  __shared__ bf16 Vt[128 * LDV];  // V^T [d=128][kv=64(+pad)], col-chunk-XOR-swizzled
  __shared__ bf16 Ps[64 * LDP];   // P [q=64][kv=64(+pad)]
  const int tid = threadIdx.x;
  const int lane = tid & 63, w = tid >> 6;
  const int quad = lane >> 4, r = lane & 15;
  const int pr = blockIdx.x, h = blockIdx.y;
  const int kvh = h >> 2;

  for (int which = 0; which < 2; ++which) {
    const int qt = which ? (31 - pr) : pr;
    const int rowq = qt * 64 + w * 16;

    // Q fragments (A-layout: m=lane&15, k=quad*8..+8) direct from global
    bf16x8 qf[4];
#pragma unroll
    for (int ks = 0; ks < 4; ++ks)
      qf[ks] = *(const bf16x8*)(qkv + (long)(rowq + r) * 6144 + h * 128 + ks * 32 + quad * 8);

    f32x4 of[8];
#pragma unroll
    for (int di = 0; di < 8; ++di) of[di] = f32x4{0.f, 0.f, 0.f, 0.f};
    float mrun[4], lrun[4];
#pragma unroll
    for (int rg = 0; rg < 4; ++rg) { mrun[rg] = -__builtin_inff(); lrun[rg] = 0.f; }

    const int ntiles = qt + 1;
    for (int kt = 0; kt < ntiles; ++kt) {
      const int kvbase = kt * 64;
      __syncthreads();  // prior tile's Ks/Vt reads (and prior which's) done

      // --- stage K via async global->LDS, XOR chunk swizzle (phys = logical ^ (row&15))
#pragma unroll
      for (int ii = 0; ii < 4; ++ii) {
        const int c = ii * 256 + tid;
        const int row = c >> 4;
        const int dcg = (c & 15) ^ (row & 15);
        gl2lds16(qkv + (long)(kvbase + row) * 6144 + 4096 + kvh * 128 + dcg * 8,
                 (char*)Ks + (ii * 256 + w * 64) * 16);
      }
      // --- stage V transposed, column-chunk XOR swizzle (jc' = jc ^ (dc&7))
#pragma unroll
      for (int ii = 0; ii < 4; ++ii) {
        const int c = ii * 256 + tid;
        const int j = c >> 4, dc = c & 15;
        bf16x8 v = *(const bf16x8*)(qkv + (long)(kvbase + j) * 6144 + 5120 + kvh * 128 + dc * 8);
        const int pc = (((j >> 3) ^ (dc & 7)) << 3) + (j & 7);
#pragma unroll
        for (int e = 0; e < 8; ++e) Vt[(dc * 8 + e) * LDV + pc] = v[e];
      }
      __syncthreads();  // staging visible

      // --- S = Q K^T (wave: 16 q x 64 kv)
      f32x4 sacc[4];
#pragma unroll
      for (int ni = 0; ni < 4; ++ni) sacc[ni] = f32x4{0.f, 0.f, 0.f, 0.f};
#pragma unroll
      for (int ks = 0; ks < 4; ++ks) {
        bf16x8 kf[4];
#pragma unroll
        for (int ni = 0; ni < 4; ++ni)
          kf[ni] = *(const bf16x8*)(&Ks[(ni * 16 + r) * 128 + (((ks * 4 + quad) ^ r) << 3)]);
#pragma unroll
        for (int ni = 0; ni < 4; ++ni) sacc[ni] = mfma16(qf[ks], kf[ni], sacc[ni]);
      }

      // --- causal mask + online softmax (rows = quad*4+rg, cols = lane&15 + ni*16)
      float mt[4];
#pragma unroll
      for (int rg = 0; rg < 4; ++rg) mt[rg] = -1e30f;
      const int rq = rowq + quad * 4;
#pragma unroll
      for (int ni = 0; ni < 4; ++ni) {
        const int ck = kvbase + ni * 16 + r;
#pragma unroll
        for (int rg = 0; rg < 4; ++rg) {
          float sv = sacc[ni][rg];
          sv = (ck > rq + rg) ? -1e30f : sv;
          sacc[ni][rg] = sv;
          mt[rg] = fmaxf(mt[rg], sv);
        }
      }
#pragma unroll
      for (int rg = 0; rg < 4; ++rg) {
        float v = mt[rg];
        v = fmaxf(v, __shfl_xor(v, 1));
        v = fmaxf(v, __shfl_xor(v, 2));
        v = fmaxf(v, __shfl_xor(v, 4));
        v = fmaxf(v, __shfl_xor(v, 8));
        mt[rg] = v;
      }
      float alpha[4], rsum[4];
#pragma unroll
      for (int rg = 0; rg < 4; ++rg) {
        const float mnew = fmaxf(mrun[rg], mt[rg]);
        alpha[rg] = __builtin_exp2f((mrun[rg] - mnew) * SCL2);
        mrun[rg] = mnew;
        rsum[rg] = 0.f;
      }
#pragma unroll
      for (int ni = 0; ni < 4; ++ni)
#pragma unroll
        for (int rg = 0; rg < 4; ++rg) {
          const float pv = __builtin_exp2f((sacc[ni][rg] - mrun[rg]) * SCL2);
          rsum[rg] += pv;
          Ps[(w * 16 + quad * 4 + rg) * LDP + ni * 16 + r] = (bf16)pv;
        }
#pragma unroll
      for (int rg = 0; rg < 4; ++rg) {
        float v = rsum[rg];
        v += __shfl_xor(v, 1);
        v += __shfl_xor(v, 2);
        v += __shfl_xor(v, 4);
        v += __shfl_xor(v, 8);
        lrun[rg] = lrun[rg] * alpha[rg] + v;
      }
#pragma unroll
      for (int di = 0; di < 8; ++di)
#pragma unroll
        for (int rg = 0; rg < 4; ++rg) of[di][rg] *= alpha[rg];

      // --- O += P * V. No barrier: wave reads only its own 16 Ps rows.
#pragma unroll
      for (int js = 0; js < 2; ++js) {
        const bf16x8 pf = *(const bf16x8*)(&Ps[(w * 16 + r) * LDP + js * 32 + quad * 8]);
#pragma unroll
        for (int di = 0; di < 8; ++di) {
          const int vrow = di * 16 + r;
          const int vcol = (((js * 4 + quad) ^ ((vrow >> 3) & 7)) << 3);
          const bf16x8 vf = *(const bf16x8*)(&Vt[vrow * LDV + vcol]);
          of[di] = mfma16(pf, vf, of[di]);
        }
      }
    }

    // --- epilogue
#pragma unroll
    for (int rg = 0; rg < 4; ++rg) {
      const float inv = 1.f / lrun[rg];
      const long t = rowq + quad * 4 + rg;
#pragma unroll
      for (int di = 0; di < 8; ++di)
        out[t * 4096 + h * 128 + di * 16 + r] = (bf16)(of[di][rg] * inv);
    }
  }
}

// ---------------- host ----------------
extern "C" void kernel_launch(void* const* d_in, const int* in_sizes, int n_in,
                              void* d_out, int out_size, void* d_ws, size_t ws_size,
                              hipStream_t stream) {
  const int* positions = (const int*)d_in[0];
  const float* hidden = (const float*)d_in[1];
  const float* w_qkv = (const float*)d_in[2];
  const float* w_o = (const float*)d_in[3];
  float* out = (float*)d_out;

  char* ws = (char*)d_ws;
  bf16* hid_b  = (bf16*)(ws);                  // 2048x4096
  bf16* wqkv_b = (bf16*)(ws + 16777216);       // 6144x4096
  bf16* wo_b   = (bf16*)(ws + 67108864);       // 4096x4096
  bf16* qkv    = (bf16*)(ws + 100663296);      // 2048x6144
  bf16* attn   = (bf16*)(ws + 125829120);      // 2048x4096

  cvt_f32_bf16<<<8388608 / 2048, 256, 0, stream>>>(hidden, hid_b, 8388608);
  cvt_f32_bf16<<<25165824 / 2048, 256, 0, stream>>>(w_qkv, wqkv_b, 25165824);
  cvt_f32_bf16<<<16777216 / 2048, 256, 0, stream>>>(w_o, wo_b, 16777216);
  gemm_bt<bf16><<<dim3(48, 16), 256, 0, stream>>>(hid_b, wqkv_b, qkv, 2048, 6144, 4096);
  rope_kernel<<<5242880 / 256, 256, 0, stream>>>(qkv, positions);
  attn_kernel<<<dim3(16, 32), 256, 0, stream>>>(qkv, attn);
  gemm_bt<float><<<dim3(32, 16), 256, 0, stream>>>(attn, wo_b, out, 2048, 4096, 4096);
}

// Round 3
// 573.446 us; speedup vs baseline: 1.3763x; 1.0200x over previous
//
#include <hip/hip_runtime.h>
#include <hip/hip_bf16.h>
#include <cstdint>

typedef __bf16 bf16;
typedef __bf16 bf16x8 __attribute__((ext_vector_type(8)));
typedef float f32x4 __attribute__((ext_vector_type(4)));

#define DEV __device__ __forceinline__

DEV f32x4 mfma16(bf16x8 a, bf16x8 b, f32x4 c) {
  return __builtin_amdgcn_mfma_f32_16x16x32_bf16(a, b, c, 0, 0, 0);
}

DEV void gl2lds16(const void* g, void* l) {
  __builtin_amdgcn_global_load_lds((__attribute__((address_space(1))) void*)g,
                                   (__attribute__((address_space(3))) void*)l,
                                   16, 0, 0);
}

// ---------------- fused fp32 -> bf16 convert, 3 segments, 8 elems/thread ----------------
DEV void cvt8(const float* __restrict__ s, bf16* __restrict__ d) {
  f32x4 a = *(const f32x4*)(s);
  f32x4 b = *(const f32x4*)(s + 4);
  bf16x8 o;
#pragma unroll
  for (int e = 0; e < 4; ++e) { o[e] = (bf16)a[e]; o[e + 4] = (bf16)b[e]; }
  *(bf16x8*)(d) = o;
}

__global__ void cvt3(const float* __restrict__ s0, bf16* __restrict__ d0, int n0,
                     const float* __restrict__ s1, bf16* __restrict__ d1, int n1,
                     const float* __restrict__ s2, bf16* __restrict__ d2) {
  long i = ((long)blockIdx.x * 256 + threadIdx.x) * 8;
  if (i < n0) { cvt8(s0 + i, d0 + i); return; }
  i -= n0;
  if (i < n1) { cvt8(s1 + i, d1 + i); return; }
  i -= n1;
  cvt8(s2 + i, d2 + i);
}

// ---------------- GEMM C = A(MxK) * B(NxK)^T ----------------
// 128x128 tile, BK=32, global_load_lds staging with XOR chunk swizzle in the
// GLOBAL address (LDS slot is fixed by lane): phys chunk pc of row holds
// logical chunk pc^(row&3) -> ds_read conflicts 4-way -> 2-way (free).
template <typename OutT>
__global__ __launch_bounds__(256) void gemm_bt(const bf16* __restrict__ A,
                                               const bf16* __restrict__ B,
                                               OutT* __restrict__ C,
                                               int M, int N, int K) {
  __shared__ bf16 As[128 * 32];
  __shared__ bf16 Bs[128 * 32];
  const int tid = threadIdx.x;
  const int lane = tid & 63, w = tid >> 6;
  const int wm = w & 1, wn = w >> 1;
  const int quad = lane >> 4, r = lane & 15;
  const long mBase = (long)blockIdx.y * 128, nBase = (long)blockIdx.x * 128;
  f32x4 acc[4][4];
#pragma unroll
  for (int i = 0; i < 4; ++i)
#pragma unroll
    for (int j = 0; j < 4; ++j) acc[i][j] = f32x4{0.f, 0.f, 0.f, 0.f};

  for (int k0 = 0; k0 < K; k0 += 32) {
    __syncthreads();
#pragma unroll
    for (int j = 0; j < 2; ++j) {
      const int c = w * 128 + j * 64 + lane;
      const int row = c >> 2, kc = c & 3;
      const int kcx = kc ^ (row & 3);  // swizzled global chunk
      gl2lds16(A + (mBase + row) * (long)K + k0 + kcx * 8,
               (char*)As + (w * 128 + j * 64) * 16);
      gl2lds16(B + (nBase + row) * (long)K + k0 + kcx * 8,
               (char*)Bs + (w * 128 + j * 64) * 16);
    }
    __syncthreads();
    bf16x8 af[4], bfr[4];
#pragma unroll
    for (int i = 0; i < 4; ++i) {
      af[i]  = *(const bf16x8*)(&As[(wm * 64 + i * 16 + r) * 32 + ((quad ^ (r & 3)) << 3)]);
      bfr[i] = *(const bf16x8*)(&Bs[(wn * 64 + i * 16 + r) * 32 + ((quad ^ (r & 3)) << 3)]);
    }
#pragma unroll
    for (int mi = 0; mi < 4; ++mi)
#pragma unroll
      for (int ni = 0; ni < 4; ++ni)
        acc[mi][ni] = mfma16(af[mi], bfr[ni], acc[mi][ni]);
  }
#pragma unroll
  for (int mi = 0; mi < 4; ++mi)
#pragma unroll
    for (int ni = 0; ni < 4; ++ni)
#pragma unroll
      for (int rg = 0; rg < 4; ++rg) {
        long row = mBase + wm * 64 + mi * 16 + quad * 4 + rg;
        long col = nBase + wn * 64 + ni * 16 + r;
        C[row * N + col] = (OutT)acc[mi][ni][rg];
      }
}

// ---------------- RoPE (neox), vectorized bf16x8 ----------------
__global__ void rope_kernel(bf16* __restrict__ qkv, const int* __restrict__ pos) {
  int idx = blockIdx.x * 256 + threadIdx.x;  // T*40*8 threads
  int g = idx & 7;
  int rest = idx >> 3;
  int head = rest % 40;
  int t = rest / 40;
  bf16* p = qkv + (long)t * 6144 + head * 128 + g * 8;
  bf16x8 a = *(const bf16x8*)(p);
  bf16x8 b = *(const bf16x8*)(p + 64);
  const float pf = (float)pos[t];
  bf16x8 oa, ob;
#pragma unroll
  for (int e = 0; e < 8; ++e) {
    const int d = g * 8 + e;
    const float invf = __builtin_expf(-(float)d * (9.210340371976184f / 64.0f));
    const float fr = pf * invf;
    const float c = __builtin_cosf(fr), s = __builtin_sinf(fr);
    const float x1 = (float)a[e], x2 = (float)b[e];
    oa[e] = (bf16)(x1 * c - x2 * s);
    ob[e] = (bf16)(x2 * c + x1 * s);
  }
  *(bf16x8*)(p) = oa;
  *(bf16x8*)(p + 64) = ob;
}

// ---------------- flash attention v3: pair-balanced + register-prefetch pipeline ----------------
// grid = (16 pairs, 32 heads), 4 waves x 16 q-rows. Next tile's K/V prefetched
// into VGPRs during compute; masking only on the diagonal tile.
__global__ __launch_bounds__(256, 2) void attn_kernel(const bf16* __restrict__ qkv,
                                                      bf16* __restrict__ out) {
  constexpr int LDV = 72, LDP = 72;
  constexpr float SCL2 = 0.08838834764831845f * 1.4426950408889634f;  // 1/sqrt(128)*log2(e)
  __shared__ bf16 Ks[64 * 128];   // [kv=64][d=128], chunk-XOR (phys = logical^(row&15))
  __shared__ bf16 Vt[128 * LDV];  // V^T [d=128][kv(+pad)], col-chunk XOR
  __shared__ bf16 Ps[64 * LDP];
  const int tid = threadIdx.x;
  const int lane = tid & 63, w = tid >> 6;
  const int quad = lane >> 4, r = lane & 15;
  const int pr = blockIdx.x, h = blockIdx.y;
  const int kvh = h >> 2;

  bf16x8 kreg[4], vreg[4];
  int srow[4], sdc[4];
#pragma unroll
  for (int ii = 0; ii < 4; ++ii) {
    const int c = ii * 256 + tid;
    srow[ii] = c >> 4;
    sdc[ii] = c & 15;
  }

  for (int which = 0; which < 2; ++which) {
    const int qt = which ? (31 - pr) : pr;
    const int rowq = qt * 64 + w * 16;

    bf16x8 qf[4];
#pragma unroll
    for (int ks = 0; ks < 4; ++ks)
      qf[ks] = *(const bf16x8*)(qkv + (long)(rowq + r) * 6144 + h * 128 + ks * 32 + quad * 8);

    f32x4 of[8];
#pragma unroll
    for (int di = 0; di < 8; ++di) of[di] = f32x4{0.f, 0.f, 0.f, 0.f};
    float mrun[4], lrun[4];
#pragma unroll
    for (int rg = 0; rg < 4; ++rg) { mrun[rg] = -__builtin_inff(); lrun[rg] = 0.f; }

    const int ntiles = qt + 1;
    // prefetch tile 0
#pragma unroll
    for (int ii = 0; ii < 4; ++ii) {
      const long rb = (long)srow[ii] * 6144 + kvh * 128;
      kreg[ii] = *(const bf16x8*)(qkv + rb + 4096 + sdc[ii] * 8);
      vreg[ii] = *(const bf16x8*)(qkv + rb + 5120 + sdc[ii] * 8);
    }

    for (int kt = 0; kt < ntiles; ++kt) {
      const int kvbase = kt * 64;
      __syncthreads();  // prior tile's LDS reads complete
      // regs -> LDS
#pragma unroll
      for (int ii = 0; ii < 4; ++ii) {
        const int row = srow[ii], dc = sdc[ii];
        *(bf16x8*)(&Ks[row * 128 + ((dc ^ (row & 15)) << 3)]) = kreg[ii];
        const int pc = (((row >> 3) ^ (dc & 7)) << 3) + (row & 7);
#pragma unroll
        for (int e = 0; e < 8; ++e) Vt[(dc * 8 + e) * LDV + pc] = vreg[ii][e];
      }
      __syncthreads();  // staging visible
      // prefetch next tile (overlaps with compute below)
      {
        const int kvn = (kt + 1 < ntiles) ? (kt + 1) * 64 : kt * 64;
#pragma unroll
        for (int ii = 0; ii < 4; ++ii) {
          const long rb = (long)(kvn + srow[ii]) * 6144 + kvh * 128;
          kreg[ii] = *(const bf16x8*)(qkv + rb + 4096 + sdc[ii] * 8);
          vreg[ii] = *(const bf16x8*)(qkv + rb + 5120 + sdc[ii] * 8);
        }
      }

      // --- S = Q K^T
      f32x4 sacc[4];
#pragma unroll
      for (int ni = 0; ni < 4; ++ni) sacc[ni] = f32x4{0.f, 0.f, 0.f, 0.f};
#pragma unroll
      for (int ks = 0; ks < 4; ++ks) {
        bf16x8 kf[4];
#pragma unroll
        for (int ni = 0; ni < 4; ++ni)
          kf[ni] = *(const bf16x8*)(&Ks[(ni * 16 + r) * 128 + (((ks * 4 + quad) ^ r) << 3)]);
#pragma unroll
        for (int ni = 0; ni < 4; ++ni) sacc[ni] = mfma16(qf[ks], kf[ni], sacc[ni]);
      }

      // --- mask (diagonal tile only) + row max
      float mt[4];
#pragma unroll
      for (int rg = 0; rg < 4; ++rg) mt[rg] = -1e30f;
      if (kt == qt) {
        const int rq = rowq + quad * 4;
#pragma unroll
        for (int ni = 0; ni < 4; ++ni) {
          const int ck = kvbase + ni * 16 + r;
#pragma unroll
          for (int rg = 0; rg < 4; ++rg) {
            float sv = sacc[ni][rg];
            sv = (ck > rq + rg) ? -1e30f : sv;
            sacc[ni][rg] = sv;
            mt[rg] = fmaxf(mt[rg], sv);
          }
        }
      } else {
#pragma unroll
        for (int ni = 0; ni < 4; ++ni)
#pragma unroll
          for (int rg = 0; rg < 4; ++rg) mt[rg] = fmaxf(mt[rg], sacc[ni][rg]);
      }
#pragma unroll
      for (int rg = 0; rg < 4; ++rg) {
        float v = mt[rg];
        v = fmaxf(v, __shfl_xor(v, 1));
        v = fmaxf(v, __shfl_xor(v, 2));
        v = fmaxf(v, __shfl_xor(v, 4));
        v = fmaxf(v, __shfl_xor(v, 8));
        mt[rg] = v;
      }
      float alpha[4], rsum[4];
#pragma unroll
      for (int rg = 0; rg < 4; ++rg) {
        const float mnew = fmaxf(mrun[rg], mt[rg]);
        alpha[rg] = __builtin_exp2f((mrun[rg] - mnew) * SCL2);
        mrun[rg] = mnew;
        rsum[rg] = 0.f;
      }
#pragma unroll
      for (int ni = 0; ni < 4; ++ni)
#pragma unroll
        for (int rg = 0; rg < 4; ++rg) {
          const float pv = __builtin_exp2f((sacc[ni][rg] - mrun[rg]) * SCL2);
          rsum[rg] += pv;
          Ps[(w * 16 + quad * 4 + rg) * LDP + ni * 16 + r] = (bf16)pv;
        }
#pragma unroll
      for (int rg = 0; rg < 4; ++rg) {
        float v = rsum[rg];
        v += __shfl_xor(v, 1);
        v += __shfl_xor(v, 2);
        v += __shfl_xor(v, 4);
        v += __shfl_xor(v, 8);
        lrun[rg] = lrun[rg] * alpha[rg] + v;
      }
#pragma unroll
      for (int di = 0; di < 8; ++di)
#pragma unroll
        for (int rg = 0; rg < 4; ++rg) of[di][rg] *= alpha[rg];

      // --- O += P * V (wave-local Ps rows, no barrier needed)
#pragma unroll
      for (int js = 0; js < 2; ++js) {
        const bf16x8 pf = *(const bf16x8*)(&Ps[(w * 16 + r) * LDP + js * 32 + quad * 8]);
#pragma unroll
        for (int di = 0; di < 8; ++di) {
          const int vrow = di * 16 + r;
          const int vcol = (((js * 4 + quad) ^ ((vrow >> 3) & 7)) << 3);
          const bf16x8 vf = *(const bf16x8*)(&Vt[vrow * LDV + vcol]);
          of[di] = mfma16(pf, vf, of[di]);
        }
      }
    }

    // --- epilogue
#pragma unroll
    for (int rg = 0; rg < 4; ++rg) {
      const float inv = 1.f / lrun[rg];
      const long t = rowq + quad * 4 + rg;
#pragma unroll
      for (int di = 0; di < 8; ++di)
        out[t * 4096 + h * 128 + di * 16 + r] = (bf16)(of[di][rg] * inv);
    }
  }
}

// ---------------- host ----------------
extern "C" void kernel_launch(void* const* d_in, const int* in_sizes, int n_in,
                              void* d_out, int out_size, void* d_ws, size_t ws_size,
                              hipStream_t stream) {
  const int* positions = (const int*)d_in[0];
  const float* hidden = (const float*)d_in[1];
  const float* w_qkv = (const float*)d_in[2];
  const float* w_o = (const float*)d_in[3];
  float* out = (float*)d_out;

  char* ws = (char*)d_ws;
  bf16* hid_b  = (bf16*)(ws);                  // 2048x4096
  bf16* wqkv_b = (bf16*)(ws + 16777216);       // 6144x4096
  bf16* wo_b   = (bf16*)(ws + 67108864);       // 4096x4096
  bf16* qkv    = (bf16*)(ws + 100663296);      // 2048x6144
  bf16* attn   = (bf16*)(ws + 125829120);      // 2048x4096

  // 50331648 total elems / 8 per thread / 256 per block
  cvt3<<<24576, 256, 0, stream>>>(hidden, hid_b, 8388608,
                                  w_qkv, wqkv_b, 25165824,
                                  w_o, wo_b);
  gemm_bt<bf16><<<dim3(48, 16), 256, 0, stream>>>(hid_b, wqkv_b, qkv, 2048, 6144, 4096);
  rope_kernel<<<2560, 256, 0, stream>>>(qkv, positions);
  attn_kernel<<<dim3(16, 32), 256, 0, stream>>>(qkv, attn);
  gemm_bt<float><<<dim3(32, 16), 256, 0, stream>>>(attn, wo_b, out, 2048, 4096, 4096);
}